// Round 3
// baseline (7544.221 us; speedup 1.0000x reference)
//
#include <hip/hip_runtime.h>

#define B_    64
#define S_    48
#define T_    48
#define E_    256
#define H_    512
#define G_    1536   // 3*H
#define VOUT_ 32000

typedef __attribute__((ext_vector_type(8))) short short8;
typedef __attribute__((ext_vector_type(4))) float f4;

__device__ inline float bfu(unsigned u) { return __uint_as_float(u << 16); }
__device__ inline unsigned short f2bf(float f) {
    unsigned u = __float_as_uint(f);
    u += 0x7fffu + ((u >> 16) & 1u);   // RNE
    return (unsigned short)(u >> 16);
}
__device__ inline unsigned pack2(float a, float b) {
    return (unsigned)f2bf(a) | ((unsigned)f2bf(b) << 16);
}

// ---------------------------------------------------------------- utility
__global__ void zero_f32(float* p, int n) {
    int i = blockIdx.x * 256 + threadIdx.x;
    if (i < n) p[i] = 0.f;
}

__global__ void zero_out_t0(float* out) {
    int v = blockIdx.x * 256 + threadIdx.x;
    int b = blockIdx.y;
    if (v < VOUT_) out[(size_t)b * T_ * VOUT_ + v] = 0.f;
}

// fp32 -> bf16, 4 elements/thread
__global__ void cvt_bf16(const float* __restrict__ s, unsigned short* __restrict__ d, int n4) {
    int i = blockIdx.x * 256 + threadIdx.x;
    if (i < n4) {
        float4 v = ((const float4*)s)[i];
        uint2 o;
        o.x = pack2(v.x, v.y);
        o.y = pack2(v.z, v.w);
        ((uint2*)d)[i] = o;
    }
}

// ---------------------------------------------------------------- MFMA GEMM
// C(M,N) = A(M,K) @ W(N,K)^T + bias
// A: fp32 (aF, optionally gathered emb[idx[(m&63)*idx_stride + (m>>6)]])
//    or bf16 (aB, direct).  W: bf16 pre-converted.  bias fp32.
// Out: fp32 row-major (outF) or fp32 seq2seq-remapped logits (outR).
// Tile 64x64, BK=32, 4 waves; wave w owns rows [16w,16w+16) x 64 cols.
__global__ __launch_bounds__(256)
void gemm64(const float* __restrict__ aF,
            const unsigned short* __restrict__ aB,
            const int* __restrict__ idx, int idx_stride,
            const unsigned short* __restrict__ Wb,
            const float* __restrict__ bias,
            float* __restrict__ outF,
            float* __restrict__ outR,
            int N, int K)
{
    __shared__ __align__(16) short As[64][40];
    __shared__ __align__(16) short Ws[64][40];
    const int tid  = threadIdx.x;
    const int m0   = blockIdx.x * 64;
    const int n0   = blockIdx.y * 64;
    const int row  = tid >> 2;
    const int col8 = (tid & 3) * 8;

    const float* apF = nullptr;
    const unsigned short* apB = nullptr;
    {
        int m = m0 + row;
        if (aF) {
            size_t r;
            if (idx) { int tt = m >> 6, b = m & 63; r = (size_t)idx[b * idx_stride + tt]; }
            else     { r = (size_t)m; }
            apF = aF + r * K + col8;
        } else {
            apB = aB + (size_t)m * K + col8;
        }
    }
    const unsigned short* wp = Wb + (size_t)(n0 + row) * K + col8;

    f4 acc[4];
    const f4 zz = {0.f, 0.f, 0.f, 0.f};
    acc[0] = zz; acc[1] = zz; acc[2] = zz; acc[3] = zz;

    const int wv   = tid >> 6;
    const int lane = tid & 63;
    const int quad = lane >> 4;
    const int l16  = lane & 15;

    for (int k0 = 0; k0 < K; k0 += 32) {
        uint4 av;
        if (apF) {
            float4 v0 = *(const float4*)(apF + k0);
            float4 v1 = *(const float4*)(apF + k0 + 4);
            av.x = pack2(v0.x, v0.y);
            av.y = pack2(v0.z, v0.w);
            av.z = pack2(v1.x, v1.y);
            av.w = pack2(v1.z, v1.w);
        } else {
            av = *(const uint4*)(apB + k0);
        }
        uint4 wvv = *(const uint4*)(wp + k0);
        *(uint4*)&As[row][col8] = av;
        *(uint4*)&Ws[row][col8] = wvv;
        __syncthreads();
        short8 afrag = *(const short8*)&As[wv * 16 + l16][quad * 8];
#pragma unroll
        for (int nt = 0; nt < 4; ++nt) {
            short8 bfrag = *(const short8*)&Ws[nt * 16 + l16][quad * 8];
            acc[nt] = __builtin_amdgcn_mfma_f32_16x16x32_bf16(afrag, bfrag, acc[nt], 0, 0, 0);
        }
        __syncthreads();
    }

#pragma unroll
    for (int nt = 0; nt < 4; ++nt) {
#pragma unroll
        for (int r = 0; r < 4; ++r) {
            int mm = m0 + wv * 16 + quad * 4 + r;
            int nn = n0 + nt * 16 + l16;
            float v = acc[nt][r];
            if (bias) v += bias[nn];
            if (outF) {
                outF[(size_t)mm * N + nn] = v;
            } else {
                int tt = mm >> 6, b = mm & 63;             // mm = t*64 + b
                outR[((size_t)b * T_ + tt + 1) * VOUT_ + nn] = v;
            }
        }
    }
}

// ---------------------------------------------------------------- GRU step
// fp32 state/activations; bf16 weights (pre-converted); fp32 biases.
__device__ inline void dot8(float& acc, uint4 v, const float* h) {
    acc = fmaf(bfu(v.x & 0xffffu), h[0], acc);
    acc = fmaf(bfu(v.x >> 16),     h[1], acc);
    acc = fmaf(bfu(v.y & 0xffffu), h[2], acc);
    acc = fmaf(bfu(v.y >> 16),     h[3], acc);
    acc = fmaf(bfu(v.z & 0xffffu), h[4], acc);
    acc = fmaf(bfu(v.z >> 16),     h[5], acc);
    acc = fmaf(bfu(v.w & 0xffffu), h[6], acc);
    acc = fmaf(bfu(v.w >> 16),     h[7], acc);
}

// One GRU layer, one timestep. grid (H/256, B), block 256.
// gi != null : precomputed fp32 gate-input preacts (B,3H) incl. bih.
// else       : compute x@Wih^T + bih here from xf (fp32 (B,H)), Wih bf16 (3H,H).
__global__ __launch_bounds__(256)
void gru_step(const float* __restrict__ gi,
              const float* __restrict__ xf,
              const unsigned short* __restrict__ Wih,
              const float* __restrict__ bih,
              const unsigned short* __restrict__ Whh,
              const float* __restrict__ bhh,
              const float* __restrict__ h_in,
              float* __restrict__ h_out,
              float* __restrict__ n_out,            // pre-mask layer output (fp32)
              unsigned short* __restrict__ y_out,   // bf16 ys at (tB+b)*H + j
              const int* __restrict__ lens,
              int t, int tB)
{
    __shared__ float hs[H_];
    __shared__ float xs[H_];
    const int b   = blockIdx.y;
    const int tid = threadIdx.x;
    const int j   = blockIdx.x * 256 + tid;

    for (int i = tid; i < H_; i += 256) hs[i] = h_in[b * H_ + i];
    if (!gi) for (int i = tid; i < H_; i += 256) xs[i] = xf[b * H_ + i];
    __syncthreads();

    // h @ Whh^T rows j, j+H, j+2H
    float ar0 = 0.f, ar1 = 0.f, az0 = 0.f, az1 = 0.f, an0 = 0.f, an1 = 0.f;
    const unsigned short* wr = Whh + (size_t)j * H_;
    const unsigned short* wz = wr + (size_t)H_ * H_;
    const unsigned short* wn = wz + (size_t)H_ * H_;
    for (int k = 0; k < H_; k += 16) {
        dot8(ar0, *(const uint4*)(wr + k),     &hs[k]);
        dot8(ar1, *(const uint4*)(wr + k + 8), &hs[k + 8]);
        dot8(az0, *(const uint4*)(wz + k),     &hs[k]);
        dot8(az1, *(const uint4*)(wz + k + 8), &hs[k + 8]);
        dot8(an0, *(const uint4*)(wn + k),     &hs[k]);
        dot8(an1, *(const uint4*)(wn + k + 8), &hs[k + 8]);
    }
    float ar = ar0 + ar1, az = az0 + az1, an = an0 + an1;

    float gr, gz, gn;
    if (gi) {
        const float* g = gi + (size_t)b * G_;
        gr = g[j]; gz = g[j + H_]; gn = g[j + 2 * H_];
    } else {
        float xr0 = 0.f, xr1 = 0.f, xz0 = 0.f, xz1 = 0.f, xn0 = 0.f, xn1 = 0.f;
        const unsigned short* ur = Wih + (size_t)j * H_;
        const unsigned short* uz = ur + (size_t)H_ * H_;
        const unsigned short* un = uz + (size_t)H_ * H_;
        for (int k = 0; k < H_; k += 16) {
            dot8(xr0, *(const uint4*)(ur + k),     &xs[k]);
            dot8(xr1, *(const uint4*)(ur + k + 8), &xs[k + 8]);
            dot8(xz0, *(const uint4*)(uz + k),     &xs[k]);
            dot8(xz1, *(const uint4*)(uz + k + 8), &xs[k + 8]);
            dot8(xn0, *(const uint4*)(un + k),     &xs[k]);
            dot8(xn1, *(const uint4*)(un + k + 8), &xs[k + 8]);
        }
        gr = xr0 + xr1 + bih[j];
        gz = xz0 + xz1 + bih[j + H_];
        gn = xn0 + xn1 + bih[j + 2 * H_];
    }

    float hr = ar + bhh[j];
    float hz = az + bhh[j + H_];
    float hn = an + bhh[j + 2 * H_];

    float rg = 1.f / (1.f + expf(-(gr + hr)));
    float zg = 1.f / (1.f + expf(-(gz + hz)));
    float ng = tanhf(gn + rg * hn);
    float hp = hs[j];
    float hnew = (1.f - zg) * ng + zg * hp;

    if (n_out) n_out[b * H_ + j] = hnew;
    if (y_out) y_out[(size_t)(tB + b) * H_ + j] = f2bf(hnew);
    float hw = hnew;
    if (lens) { if (t >= lens[b]) hw = hp; }
    h_out[b * H_ + j] = hw;
}

// ---------------------------------------------------------------- launch
static inline void cvt(const float* s, unsigned short* d, int n, hipStream_t st) {
    int n4 = n / 4;
    cvt_bf16<<<dim3((n4 + 255) / 256), 256, 0, st>>>(s, d, n4);
}

extern "C" void kernel_launch(void* const* d_in, const int* in_sizes, int n_in,
                              void* d_out, int out_size, void* d_ws, size_t ws_size,
                              hipStream_t stream)
{
    const int* source  = (const int*)d_in[0];
    const int* target  = (const int*)d_in[1];
    const int* src_len = (const int*)d_in[2];
    const float* enc_emb  = (const float*)d_in[3];
    const float* enc_Wih0 = (const float*)d_in[4];
    const float* enc_Whh0 = (const float*)d_in[5];
    const float* enc_bih0 = (const float*)d_in[6];
    const float* enc_bhh0 = (const float*)d_in[7];
    const float* enc_Wih1 = (const float*)d_in[8];
    const float* enc_Whh1 = (const float*)d_in[9];
    const float* enc_bih1 = (const float*)d_in[10];
    const float* enc_bhh1 = (const float*)d_in[11];
    const float* dec_emb  = (const float*)d_in[12];
    const float* dec_Wih0 = (const float*)d_in[13];
    const float* dec_Whh0 = (const float*)d_in[14];
    const float* dec_bih0 = (const float*)d_in[15];
    const float* dec_bhh0 = (const float*)d_in[16];
    const float* dec_Wih1 = (const float*)d_in[17];
    const float* dec_Whh1 = (const float*)d_in[18];
    const float* dec_bih1 = (const float*)d_in[19];
    const float* dec_bhh1 = (const float*)d_in[20];
    const float* fc_W     = (const float*)d_in[21];
    const float* fc_b     = (const float*)d_in[22];
    float* out = (float*)d_out;

    // ---- workspace layout (~66 MB) ----
    char* w = (char*)d_ws;
    float* hbase  = (float*)w;                w += (size_t)4 * B_ * H_ * 4;
    float* n0buf  = (float*)w;                w += (size_t)B_ * H_ * 4;
    float* gi_buf = (float*)w;                w += (size_t)S_ * B_ * G_ * 4;
    unsigned short* ys = (unsigned short*)w;  w += (size_t)(T_ - 1) * B_ * H_ * 2;
    unsigned short* eWih0b = (unsigned short*)w; w += (size_t)G_ * E_ * 2;
    unsigned short* dWih0b = (unsigned short*)w; w += (size_t)G_ * E_ * 2;
    unsigned short* eWih1b = (unsigned short*)w; w += (size_t)G_ * H_ * 2;
    unsigned short* eWhh0b = (unsigned short*)w; w += (size_t)G_ * H_ * 2;
    unsigned short* eWhh1b = (unsigned short*)w; w += (size_t)G_ * H_ * 2;
    unsigned short* dWih1b = (unsigned short*)w; w += (size_t)G_ * H_ * 2;
    unsigned short* dWhh0b = (unsigned short*)w; w += (size_t)G_ * H_ * 2;
    unsigned short* dWhh1b = (unsigned short*)w; w += (size_t)G_ * H_ * 2;
    unsigned short* fcWb   = (unsigned short*)w;

    float* h0buf[2] = { hbase,               hbase + B_ * H_ };
    float* h1buf[2] = { hbase + 2 * B_ * H_, hbase + 3 * B_ * H_ };

    // weight conversions (fp32 -> bf16)
    cvt(enc_Wih0, eWih0b, G_ * E_, stream);
    cvt(dec_Wih0, dWih0b, G_ * E_, stream);
    cvt(enc_Wih1, eWih1b, G_ * H_, stream);
    cvt(enc_Whh0, eWhh0b, G_ * H_, stream);
    cvt(enc_Whh1, eWhh1b, G_ * H_, stream);
    cvt(dec_Wih1, dWih1b, G_ * H_, stream);
    cvt(dec_Whh0, dWhh0b, G_ * H_, stream);
    cvt(dec_Whh1, dWhh1b, G_ * H_, stream);
    cvt(fc_W,     fcWb,   VOUT_ * H_, stream);

    zero_f32<<<dim3((4 * B_ * H_ + 255) / 256), 256, 0, stream>>>(hbase, 4 * B_ * H_);
    zero_out_t0<<<dim3((VOUT_ + 255) / 256, B_), 256, 0, stream>>>(out);

    const dim3 sgrid(H_ / 256, B_);

    // ======== encoder ========
    gemm64<<<dim3(S_ * B_ / 64, G_ / 64), 256, 0, stream>>>(
        enc_emb, nullptr, source, S_, eWih0b, enc_bih0, gi_buf, nullptr, G_, E_);

    int p0 = 0, p1 = 0;
    for (int t = 0; t < S_; ++t) {
        gru_step<<<sgrid, 256, 0, stream>>>(
            gi_buf + (size_t)t * B_ * G_, nullptr, nullptr, nullptr,
            eWhh0b, enc_bhh0, h0buf[p0], h0buf[1 - p0], n0buf, nullptr, src_len, t, 0);
        gru_step<<<sgrid, 256, 0, stream>>>(
            nullptr, n0buf, eWih1b, enc_bih1,
            eWhh1b, enc_bhh1, h1buf[p1], h1buf[1 - p1], nullptr, nullptr, src_len, t, 0);
        p0 ^= 1; p1 ^= 1;
    }

    // ======== decoder ========
    gemm64<<<dim3((T_ - 1) * B_ / 64, G_ / 64), 256, 0, stream>>>(
        dec_emb, nullptr, target, T_, dWih0b, dec_bih0, gi_buf, nullptr, G_, E_);

    for (int t = 0; t < T_ - 1; ++t) {
        gru_step<<<sgrid, 256, 0, stream>>>(
            gi_buf + (size_t)t * B_ * G_, nullptr, nullptr, nullptr,
            dWhh0b, dec_bhh0, h0buf[p0], h0buf[1 - p0], n0buf, nullptr, nullptr, t, 0);
        gru_step<<<sgrid, 256, 0, stream>>>(
            nullptr, n0buf, dWih1b, dec_bih1,
            dWhh1b, dec_bhh1, h1buf[p1], h1buf[1 - p1], nullptr, ys, nullptr, t, t * B_);
        p0 ^= 1; p1 ^= 1;
    }

    // ======== logits = ys @ fc_W^T + fc_b -> out[b, t+1, :] ========
    gemm64<<<dim3((T_ - 1) * B_ / 64, VOUT_ / 64), 256, 0, stream>>>(
        nullptr, ys, nullptr, 0, fcWb, fc_b, nullptr, out, VOUT_, H_);
}

// Round 4
// 6311.586 us; speedup vs baseline: 1.1953x; 1.1953x over previous
//
#include <hip/hip_runtime.h>

#define B_    64
#define S_    48
#define T_    48
#define E_    256
#define H_    512
#define G_    1536   // 3*H
#define VOUT_ 32000

typedef __attribute__((ext_vector_type(8))) short short8;
typedef __attribute__((ext_vector_type(4))) float f4;

__device__ inline float bfu(unsigned u) { return __uint_as_float(u << 16); }
__device__ inline unsigned short f2bf(float f) {
    unsigned u = __float_as_uint(f);
    u += 0x7fffu + ((u >> 16) & 1u);   // RNE
    return (unsigned short)(u >> 16);
}
__device__ inline unsigned pack2(float a, float b) {
    return (unsigned)f2bf(a) | ((unsigned)f2bf(b) << 16);
}

// ---------------------------------------------------------------- utility
__global__ void zero_f32(float* p, int n) {
    int i = blockIdx.x * 256 + threadIdx.x;
    if (i < n) p[i] = 0.f;
}

__global__ void zero_out_t0(float* out) {
    int v = blockIdx.x * 256 + threadIdx.x;
    int b = blockIdx.y;
    if (v < VOUT_) out[(size_t)b * T_ * VOUT_ + v] = 0.f;
}

// fp32 -> bf16, 4 elements/thread
__global__ void cvt_bf16(const float* __restrict__ s, unsigned short* __restrict__ d, int n4) {
    int i = blockIdx.x * 256 + threadIdx.x;
    if (i < n4) {
        float4 v = ((const float4*)s)[i];
        uint2 o;
        o.x = pack2(v.x, v.y);
        o.y = pack2(v.z, v.w);
        ((uint2*)d)[i] = o;
    }
}

// ---------------------------------------------------------------- MFMA GEMM
// C(M,N) = A(M,K) @ W(N,K)^T + bias   (used for gi precompute + logits)
__global__ __launch_bounds__(256)
void gemm64(const float* __restrict__ aF,
            const unsigned short* __restrict__ aB,
            const int* __restrict__ idx, int idx_stride,
            const unsigned short* __restrict__ Wb,
            const float* __restrict__ bias,
            float* __restrict__ outF,
            float* __restrict__ outR,
            int N, int K)
{
    __shared__ __align__(16) short As[64][40];
    __shared__ __align__(16) short Ws[64][40];
    const int tid  = threadIdx.x;
    const int m0   = blockIdx.x * 64;
    const int n0   = blockIdx.y * 64;
    const int row  = tid >> 2;
    const int col8 = (tid & 3) * 8;

    const float* apF = nullptr;
    const unsigned short* apB = nullptr;
    {
        int m = m0 + row;
        if (aF) {
            size_t r;
            if (idx) { int tt = m >> 6, b = m & 63; r = (size_t)idx[b * idx_stride + tt]; }
            else     { r = (size_t)m; }
            apF = aF + r * K + col8;
        } else {
            apB = aB + (size_t)m * K + col8;
        }
    }
    const unsigned short* wp = Wb + (size_t)(n0 + row) * K + col8;

    f4 acc[4];
    const f4 zz = {0.f, 0.f, 0.f, 0.f};
    acc[0] = zz; acc[1] = zz; acc[2] = zz; acc[3] = zz;

    const int wv   = tid >> 6;
    const int lane = tid & 63;
    const int quad = lane >> 4;
    const int l16  = lane & 15;

    for (int k0 = 0; k0 < K; k0 += 32) {
        uint4 av;
        if (apF) {
            float4 v0 = *(const float4*)(apF + k0);
            float4 v1 = *(const float4*)(apF + k0 + 4);
            av.x = pack2(v0.x, v0.y);
            av.y = pack2(v0.z, v0.w);
            av.z = pack2(v1.x, v1.y);
            av.w = pack2(v1.z, v1.w);
        } else {
            av = *(const uint4*)(apB + k0);
        }
        uint4 wvv = *(const uint4*)(wp + k0);
        *(uint4*)&As[row][col8] = av;
        *(uint4*)&Ws[row][col8] = wvv;
        __syncthreads();
        short8 afrag = *(const short8*)&As[wv * 16 + l16][quad * 8];
#pragma unroll
        for (int nt = 0; nt < 4; ++nt) {
            short8 bfrag = *(const short8*)&Ws[nt * 16 + l16][quad * 8];
            acc[nt] = __builtin_amdgcn_mfma_f32_16x16x32_bf16(afrag, bfrag, acc[nt], 0, 0, 0);
        }
        __syncthreads();
    }

#pragma unroll
    for (int nt = 0; nt < 4; ++nt) {
#pragma unroll
        for (int r = 0; r < 4; ++r) {
            int mm = m0 + wv * 16 + quad * 4 + r;
            int nn = n0 + nt * 16 + l16;
            float v = acc[nt][r];
            if (bias) v += bias[nn];
            if (outF) {
                outF[(size_t)mm * N + nn] = v;
            } else {
                int tt = mm >> 6, b = mm & 63;             // mm = t*64 + b
                outR[((size_t)b * T_ + tt + 1) * VOUT_ + nn] = v;
            }
        }
    }
}

// ---------------------------------------------------------------- fused GRU step (MFMA)
// One layer, one timestep, ALL batches. grid = 8 blocks, 256 threads (4 waves).
// Block bn owns hidden cols j in [64*bn, 64*bn+64). Computes, for all 64 batches:
//   acc0 = r-gate GEMM sum over phases, acc1 = z-gate, acc2 = input-part n, acc3 = hidden-part n.
// Phase 0: A0(64x512 bf16) @ W0(1536x512 bf16)^T   (layer0: h@Whh; layer1: x@Wih)
// Phase 1 (A1!=null): A1 @ W1^T                    (layer1: h@Whh)
// layer0 (gi!=null): gi (64xG fp32) holds x@Wih+bih; n-acc of phase0 goes to acc3.
// layer1: n-acc of phase0 -> acc2 (input), phase1 -> acc3 (hidden); bih added here.
// Epilogue: r=sig(acc0+b), z=sig(acc1+b), n=tanh(inn + r*hn), h'=(1-z)n+z*h.
__global__ __launch_bounds__(256)
void rnn_step(const unsigned short* __restrict__ A0,
              const unsigned short* __restrict__ W0,
              const unsigned short* __restrict__ A1,
              const unsigned short* __restrict__ W1,
              const float* __restrict__ gi,
              const float* __restrict__ bihf,
              const float* __restrict__ bhhf,
              const float* __restrict__ h_prev,
              float* __restrict__ h_out_f,
              unsigned short* __restrict__ h_out_b,
              unsigned short* __restrict__ n_out_b,
              unsigned short* __restrict__ ys,
              const int* __restrict__ lens,
              int t, int tB)
{
    __shared__ __align__(16) short As[64][72];
    __shared__ __align__(16) short Ws[3][64][72];

    const int tid = threadIdx.x;
    const int j0  = blockIdx.x * 64;
    const int row = tid >> 2;
    const int c16 = (tid & 3) * 16;
    const int wv   = tid >> 6;
    const int lane = tid & 63;
    const int quad = lane >> 4;
    const int l16  = lane & 15;

    f4 acc[4][4];
    const f4 zz = {0.f, 0.f, 0.f, 0.f};
#pragma unroll
    for (int a = 0; a < 4; ++a)
#pragma unroll
        for (int nt = 0; nt < 4; ++nt) acc[a][nt] = zz;

    const int nPh = A1 ? 2 : 1;
    for (int p = 0; p < nPh; ++p) {
        const unsigned short* Ap = p ? A1 : A0;
        const unsigned short* Wp = p ? W1 : W0;
        const int nIdx = (A1 && p == 0) ? 2 : 3;   // where the n-gate accumulates

        for (int k0 = 0; k0 < H_; k0 += 64) {
            const unsigned short* ap = Ap + (size_t)row * H_ + k0 + c16;
            *(uint4*)&As[row][c16]     = *(const uint4*)(ap);
            *(uint4*)&As[row][c16 + 8] = *(const uint4*)(ap + 8);
#pragma unroll
            for (int g = 0; g < 3; ++g) {
                const unsigned short* wp = Wp + (size_t)(g * H_ + j0 + row) * H_ + k0 + c16;
                *(uint4*)&Ws[g][row][c16]     = *(const uint4*)(wp);
                *(uint4*)&Ws[g][row][c16 + 8] = *(const uint4*)(wp + 8);
            }
            __syncthreads();
#pragma unroll
            for (int ks = 0; ks < 2; ++ks) {
                short8 af = *(const short8*)&As[wv * 16 + l16][ks * 32 + quad * 8];
#pragma unroll
                for (int g = 0; g < 3; ++g) {
                    const int ai = (g == 2) ? nIdx : g;
#pragma unroll
                    for (int nt = 0; nt < 4; ++nt) {
                        short8 bf = *(const short8*)&Ws[g][nt * 16 + l16][ks * 32 + quad * 8];
                        acc[ai][nt] = __builtin_amdgcn_mfma_f32_16x16x32_bf16(af, bf, acc[ai][nt], 0, 0, 0);
                    }
                }
            }
            __syncthreads();
        }
    }

    // -------- epilogue: fused gates --------
#pragma unroll
    for (int nt = 0; nt < 4; ++nt) {
        const int j = j0 + nt * 16 + l16;
        float br = bhhf[j];
        float bz = bhhf[j + H_];
        float bn = bhhf[j + 2 * H_];
        float ir_b = 0.f, iz_b = 0.f, in_b = 0.f;
        if (bihf) { ir_b = bihf[j]; iz_b = bihf[j + H_]; in_b = bihf[j + 2 * H_]; }
#pragma unroll
        for (int r = 0; r < 4; ++r) {
            const int m = wv * 16 + quad * 4 + r;
            float pr = acc[0][nt][r] + br + ir_b;
            float pz = acc[1][nt][r] + bz + iz_b;
            float inn = acc[2][nt][r] + in_b;
            float hn  = acc[3][nt][r] + bn;
            if (gi) {
                const float* g = gi + (size_t)m * G_;
                pr  += g[j];
                pz  += g[j + H_];
                inn += g[j + 2 * H_];
            }
            float rg = 1.f / (1.f + expf(-pr));
            float zg = 1.f / (1.f + expf(-pz));
            float ng = tanhf(inn + rg * hn);
            float hp = h_prev[m * H_ + j];
            float hnew = (1.f - zg) * ng + zg * hp;

            if (n_out_b) n_out_b[m * H_ + j] = f2bf(hnew);
            if (ys)      ys[(size_t)(tB + m) * H_ + j] = f2bf(hnew);
            float hw = hnew;
            if (lens) { if (t >= lens[m]) hw = hp; }
            h_out_f[m * H_ + j] = hw;
            h_out_b[m * H_ + j] = f2bf(hw);
        }
    }
}

// ---------------------------------------------------------------- launch
static inline void cvt(const float* s, unsigned short* d, int n, hipStream_t st) {
    int n4 = n / 4;
    cvt_bf16<<<dim3((n4 + 255) / 256), 256, 0, st>>>(s, d, n4);
}

extern "C" void kernel_launch(void* const* d_in, const int* in_sizes, int n_in,
                              void* d_out, int out_size, void* d_ws, size_t ws_size,
                              hipStream_t stream)
{
    const int* source  = (const int*)d_in[0];
    const int* target  = (const int*)d_in[1];
    const int* src_len = (const int*)d_in[2];
    const float* enc_emb  = (const float*)d_in[3];
    const float* enc_Wih0 = (const float*)d_in[4];
    const float* enc_Whh0 = (const float*)d_in[5];
    const float* enc_bih0 = (const float*)d_in[6];
    const float* enc_bhh0 = (const float*)d_in[7];
    const float* enc_Wih1 = (const float*)d_in[8];
    const float* enc_Whh1 = (const float*)d_in[9];
    const float* enc_bih1 = (const float*)d_in[10];
    const float* enc_bhh1 = (const float*)d_in[11];
    const float* dec_emb  = (const float*)d_in[12];
    const float* dec_Wih0 = (const float*)d_in[13];
    const float* dec_Whh0 = (const float*)d_in[14];
    const float* dec_bih0 = (const float*)d_in[15];
    const float* dec_bhh0 = (const float*)d_in[16];
    const float* dec_Wih1 = (const float*)d_in[17];
    const float* dec_Whh1 = (const float*)d_in[18];
    const float* dec_bih1 = (const float*)d_in[19];
    const float* dec_bhh1 = (const float*)d_in[20];
    const float* fc_W     = (const float*)d_in[21];
    const float* fc_b     = (const float*)d_in[22];
    float* out = (float*)d_out;

    const size_t BH = (size_t)B_ * H_;   // 32768

    // ---- workspace layout (bytes) ----
    char* w = (char*)d_ws;
    float* h0f[2]; float* h1f[2];
    unsigned short* h0b[2]; unsigned short* h1b[2];
    h0f[0] = (float*)w;          w += BH * 4;
    h1f[0] = (float*)w;          w += BH * 4;
    h0b[0] = (unsigned short*)w; w += BH * 2;
    h1b[0] = (unsigned short*)w; w += BH * 2;      // [0..384KB) zeroed as one region
    h0f[1] = (float*)w;          w += BH * 4;
    h1f[1] = (float*)w;          w += BH * 4;
    h0b[1] = (unsigned short*)w; w += BH * 2;
    h1b[1] = (unsigned short*)w; w += BH * 2;
    unsigned short* n0b = (unsigned short*)w; w += BH * 2;
    float* gi_buf = (float*)w;                w += (size_t)S_ * B_ * G_ * 4;
    unsigned short* ys = (unsigned short*)w;  w += (size_t)(T_ - 1) * B_ * H_ * 2;
    unsigned short* eWih0b = (unsigned short*)w; w += (size_t)G_ * E_ * 2;
    unsigned short* dWih0b = (unsigned short*)w; w += (size_t)G_ * E_ * 2;
    unsigned short* eWih1b = (unsigned short*)w; w += (size_t)G_ * H_ * 2;
    unsigned short* eWhh0b = (unsigned short*)w; w += (size_t)G_ * H_ * 2;
    unsigned short* eWhh1b = (unsigned short*)w; w += (size_t)G_ * H_ * 2;
    unsigned short* dWih1b = (unsigned short*)w; w += (size_t)G_ * H_ * 2;
    unsigned short* dWhh0b = (unsigned short*)w; w += (size_t)G_ * H_ * 2;
    unsigned short* dWhh1b = (unsigned short*)w; w += (size_t)G_ * H_ * 2;
    unsigned short* fcWb   = (unsigned short*)w;

    // weight conversions (fp32 -> bf16)
    cvt(enc_Wih0, eWih0b, G_ * E_, stream);
    cvt(dec_Wih0, dWih0b, G_ * E_, stream);
    cvt(enc_Wih1, eWih1b, G_ * H_, stream);
    cvt(enc_Whh0, eWhh0b, G_ * H_, stream);
    cvt(enc_Whh1, eWhh1b, G_ * H_, stream);
    cvt(dec_Wih1, dWih1b, G_ * H_, stream);
    cvt(dec_Whh0, dWhh0b, G_ * H_, stream);
    cvt(dec_Whh1, dWhh1b, G_ * H_, stream);
    cvt(fc_W,     fcWb,   VOUT_ * H_, stream);

    // zero initial states: h0f[0], h1f[0], h0b[0], h1b[0] are contiguous = 3*BH floats
    zero_f32<<<dim3((int)((3 * BH + 255) / 256)), 256, 0, stream>>>((float*)d_ws, (int)(3 * BH));
    zero_out_t0<<<dim3((VOUT_ + 255) / 256, B_), 256, 0, stream>>>(out);

    // ======== encoder ========
    gemm64<<<dim3(S_ * B_ / 64, G_ / 64), 256, 0, stream>>>(
        enc_emb, nullptr, source, S_, eWih0b, enc_bih0, gi_buf, nullptr, G_, E_);

    int p0 = 0, p1 = 0;
    for (int t = 0; t < S_; ++t) {
        rnn_step<<<8, 256, 0, stream>>>(
            h0b[p0], eWhh0b, nullptr, nullptr,
            gi_buf + (size_t)t * B_ * G_, nullptr, enc_bhh0,
            h0f[p0], h0f[1 - p0], h0b[1 - p0], n0b, nullptr, src_len, t, 0);
        rnn_step<<<8, 256, 0, stream>>>(
            n0b, eWih1b, h1b[p1], eWhh1b,
            nullptr, enc_bih1, enc_bhh1,
            h1f[p1], h1f[1 - p1], h1b[1 - p1], nullptr, nullptr, src_len, t, 0);
        p0 ^= 1; p1 ^= 1;
    }

    // ======== decoder ========
    gemm64<<<dim3((T_ - 1) * B_ / 64, G_ / 64), 256, 0, stream>>>(
        dec_emb, nullptr, target, T_, dWih0b, dec_bih0, gi_buf, nullptr, G_, E_);

    for (int t = 0; t < T_ - 1; ++t) {
        rnn_step<<<8, 256, 0, stream>>>(
            h0b[p0], dWhh0b, nullptr, nullptr,
            gi_buf + (size_t)t * B_ * G_, nullptr, dec_bhh0,
            h0f[p0], h0f[1 - p0], h0b[1 - p0], n0b, nullptr, nullptr, t, 0);
        rnn_step<<<8, 256, 0, stream>>>(
            n0b, dWih1b, h1b[p1], dWhh1b,
            nullptr, dec_bih1, dec_bhh1,
            h1f[p1], h1f[1 - p1], h1b[1 - p1], nullptr, ys, nullptr, t, t * B_);
        p0 ^= 1; p1 ^= 1;
    }

    // ======== logits = ys @ fc_W^T + fc_b -> out[b, t+1, :] ========
    gemm64<<<dim3((T_ - 1) * B_ / 64, VOUT_ / 64), 256, 0, stream>>>(
        nullptr, ys, nullptr, 0, fcWb, fc_b, nullptr, out, VOUT_, H_);
}